// Round 1
// baseline (252.963 us; speedup 1.0000x reference)
//
#include <hip/hip_runtime.h>
#include <hip/hip_bf16.h>
#include <cstdint>

typedef __bf16 bf16;
typedef __bf16 bf16x8 __attribute__((ext_vector_type(8)));
typedef float f32x4 __attribute__((ext_vector_type(4)));

#define DM   1024
#define SEQ  2048
#define NH   16
#define DKH  64
#define MTOK 4096   // B*S

__device__ __forceinline__ bf16x8 ld8(const bf16* p) {
    return *reinterpret_cast<const bf16x8*>(p);
}

// async global->LDS, 16B per lane (wave-uniform LDS base + lane*16 layout)
__device__ __forceinline__ void gld16(const void* g, void* lds) {
    __builtin_amdgcn_global_load_lds(
        (__attribute__((address_space(1))) void*)(uintptr_t)g,
        (__attribute__((address_space(3))) void*)(uint32_t)(uintptr_t)lds,
        16, 0, 0);
}

__device__ __forceinline__ f32x4 mfma16(bf16x8 a, bf16x8 b, f32x4 c) {
    return __builtin_amdgcn_mfma_f32_16x16x32_bf16(a, b, c, 0, 0, 0);
}

// ---------------- fp32 -> bf16 cast (vectorized) ----------------
__global__ __launch_bounds__(256) void cvt4(const float4* __restrict__ src,
                                            ushort4* __restrict__ dst, int n4) {
    int i = blockIdx.x * 256 + threadIdx.x;
    if (i >= n4) return;
    float4 f = src[i];
    ushort4 u;
    u.x = __builtin_bit_cast(unsigned short, (bf16)f.x);
    u.y = __builtin_bit_cast(unsigned short, (bf16)f.y);
    u.z = __builtin_bit_cast(unsigned short, (bf16)f.z);
    u.w = __builtin_bit_cast(unsigned short, (bf16)f.w);
    dst[i] = u;
}

// ---------------- GEMM: y = A @ W^T + bias  (A: Mx1024, W: Nx1024 row-major) ----
// 128x128 tile, BK=64, 4 waves (2x2), 16x16x32 bf16 MFMA, global_load_lds staging.
template <bool OUT_F32>
__device__ __forceinline__ void gemm_body(const bf16* __restrict__ A,
                                          const bf16* __restrict__ W,
                                          const float* __restrict__ bias,
                                          void* __restrict__ outp,
                                          int m0, int n0) {
    constexpr int K = DM, BK = 64;
    __shared__ __attribute__((aligned(16))) bf16 As[128 * BK];
    __shared__ __attribute__((aligned(16))) bf16 Bs[128 * BK];

    const int t     = threadIdx.x;
    const int lane  = t & 63;
    const int row16 = lane & 15, grp = lane >> 4;
    const int wave  = t >> 6;
    const int wr    = (wave >> 1) * 64;
    const int wc    = (wave & 1) * 64;

    f32x4 acc[4][4] = {};

    const int sr = t >> 3;         // staging row (+= 32 per issue)
    const int sc = (t & 7) * 8;    // staging col (bf16 elems)
    const bf16* Ag = A + (size_t)(m0 + sr) * K + sc;
    const bf16* Wg = W + (size_t)(n0 + sr) * K + sc;
    bf16* Asw = &As[t * 8];
    bf16* Bsw = &Bs[t * 8];

    for (int kt = 0; kt < K; kt += BK) {
        __syncthreads();
#pragma unroll
        for (int i = 0; i < 4; ++i) {
            gld16(Ag + (size_t)i * 32 * K + kt, Asw + i * 2048);
            gld16(Wg + (size_t)i * 32 * K + kt, Bsw + i * 2048);
        }
        __syncthreads();
#pragma unroll
        for (int kk = 0; kk < BK; kk += 32) {
            bf16x8 af[4], bfr[4];
#pragma unroll
            for (int m = 0; m < 4; ++m)
                af[m] = ld8(&As[(wr + m * 16 + row16) * BK + kk + grp * 8]);
#pragma unroll
            for (int n = 0; n < 4; ++n)
                bfr[n] = ld8(&Bs[(wc + n * 16 + row16) * BK + kk + grp * 8]);
#pragma unroll
            for (int m = 0; m < 4; ++m)
#pragma unroll
                for (int n = 0; n < 4; ++n)
                    acc[m][n] = mfma16(af[m], bfr[n], acc[m][n]);
        }
    }

#pragma unroll
    for (int n = 0; n < 4; ++n) {
        const int col = n0 + wc + n * 16 + row16;
        const float bv = bias[col];
#pragma unroll
        for (int m = 0; m < 4; ++m) {
            const int row = m0 + wr + m * 16 + grp * 4;
#pragma unroll
            for (int j = 0; j < 4; ++j) {
                float v = acc[m][n][j] + bv;
                if constexpr (OUT_F32)
                    ((float*)outp)[(size_t)(row + j) * DM + col] = v;
                else
                    ((bf16*)outp)[(size_t)(row + j) * DM + col] = (bf16)v;
            }
        }
    }
}

__global__ __launch_bounds__(256) void gemm_qkv(
    const bf16* __restrict__ xb,
    const bf16* __restrict__ wqb, const bf16* __restrict__ wkb, const bf16* __restrict__ wvb,
    const float* __restrict__ bq, const float* __restrict__ bk, const float* __restrict__ bv,
    bf16* __restrict__ q, bf16* __restrict__ k, bf16* __restrict__ v) {
    const int sel = blockIdx.y >> 3;
    const bf16* W    = sel == 0 ? wqb : (sel == 1 ? wkb : wvb);
    const float* bia = sel == 0 ? bq  : (sel == 1 ? bk  : bv);
    bf16* out        = sel == 0 ? q   : (sel == 1 ? k   : v);
    gemm_body<false>(xb, W, bia, out, blockIdx.x * 128, (blockIdx.y & 7) * 128);
}

__global__ __launch_bounds__(256) void gemm_out(
    const bf16* __restrict__ ab, const bf16* __restrict__ wob,
    const float* __restrict__ bo, float* __restrict__ out) {
    gemm_body<true>(ab, wob, bo, out, blockIdx.x * 128, blockIdx.y * 128);
}

// ---------------- flash attention ----------------
// grid: (S/64, H, B), 256 threads = 4 waves, each wave owns 16 q-rows.
// Q,K,V,O are token-major [4096][1024] bf16; head h = columns [h*64, h*64+64).
__global__ __launch_bounds__(256) void attn(const bf16* __restrict__ Q,
                                            const bf16* __restrict__ K,
                                            const bf16* __restrict__ V,
                                            bf16* __restrict__ O) {
    constexpr int LDK = 72;           // padded LDS row stride (2-way banks only)
    constexpr float SCALE = 0.125f;   // 1/sqrt(64)
    __shared__ __attribute__((aligned(16))) bf16 Ks[64 * LDK];    // [kv][d]
    __shared__ __attribute__((aligned(16))) bf16 VTs[64 * LDK];   // [d][kv]
    __shared__ __attribute__((aligned(16))) bf16 Ps[4][16 * LDK]; // per-wave P [q][kv]

    const int t = threadIdx.x;
    const int lane = t & 63, wave = t >> 6;
    const int row16 = lane & 15, grp = lane >> 4;
    const int b = blockIdx.z, h = blockIdx.y;
    const int q0 = blockIdx.x * 64;

    const size_t hoff = (size_t)h * DKH;
    const bf16* Qb = Q + (size_t)b * SEQ * DM + hoff;
    const bf16* Kb = K + (size_t)b * SEQ * DM + hoff;
    const bf16* Vb = V + (size_t)b * SEQ * DM + hoff;

    // Q A-fragments: row = lane&15, k = grp*8.. (two K=32 chunks cover d=0..63)
    const bf16* qrow = Qb + (size_t)(q0 + wave * 16 + row16) * DM + grp * 8;
    const bf16x8 qf0 = ld8(qrow);
    const bf16x8 qf1 = ld8(qrow + 32);

    f32x4 o[4] = {};
    float mrow[4] = {-1e30f, -1e30f, -1e30f, -1e30f};
    float lrow[4] = {};

    const int sr = t >> 3;        // kv row for staging (+32 for i=1)
    const int sc = (t & 7) * 8;   // d col for staging

    for (int kt = 0; kt < SEQ; kt += 64) {
        __syncthreads();
        // stage K row-major (padded) and V transposed
#pragma unroll
        for (int i = 0; i < 2; ++i) {
            const int r = i * 32 + sr;
            bf16x8 kv = ld8(Kb + (size_t)(kt + r) * DM + sc);
            *reinterpret_cast<bf16x8*>(&Ks[r * LDK + sc]) = kv;
            bf16x8 vv = ld8(Vb + (size_t)(kt + r) * DM + sc);
#pragma unroll
            for (int j = 0; j < 8; ++j) VTs[(sc + j) * LDK + r] = vv[j];
        }
        __syncthreads();

        // S = Q K^T : 16 q-rows x 64 kv-cols
        f32x4 s[4];
#pragma unroll
        for (int n = 0; n < 4; ++n) {
            f32x4 a = {};
            a = mfma16(qf0, ld8(&Ks[(n * 16 + row16) * LDK + grp * 8]), a);
            a = mfma16(qf1, ld8(&Ks[(n * 16 + row16) * LDK + 32 + grp * 8]), a);
            s[n] = a;
        }

        // online softmax (rows = grp*4+j, reduce over 16 lanes of row16)
        float rmax[4];
#pragma unroll
        for (int j = 0; j < 4; ++j)
            rmax[j] = fmaxf(fmaxf(s[0][j], s[1][j]), fmaxf(s[2][j], s[3][j])) * SCALE;
#pragma unroll
        for (int msk = 1; msk < 16; msk <<= 1)
#pragma unroll
            for (int j = 0; j < 4; ++j)
                rmax[j] = fmaxf(rmax[j], __shfl_xor(rmax[j], msk));

        float alpha[4], rsum[4] = {};
#pragma unroll
        for (int j = 0; j < 4; ++j) {
            float mn = fmaxf(mrow[j], rmax[j]);
            alpha[j] = __expf(mrow[j] - mn);
            mrow[j] = mn;
        }
        float p[4][4];
#pragma unroll
        for (int n = 0; n < 4; ++n)
#pragma unroll
            for (int j = 0; j < 4; ++j) {
                float e = __expf(s[n][j] * SCALE - mrow[j]);
                p[n][j] = e;
                rsum[j] += e;
            }
#pragma unroll
        for (int msk = 1; msk < 16; msk <<= 1)
#pragma unroll
            for (int j = 0; j < 4; ++j) rsum[j] += __shfl_xor(rsum[j], msk);
#pragma unroll
        for (int j = 0; j < 4; ++j) lrow[j] = lrow[j] * alpha[j] + rsum[j];
#pragma unroll
        for (int n = 0; n < 4; ++n)
#pragma unroll
            for (int j = 0; j < 4; ++j) o[n][j] *= alpha[j];

        // P -> per-wave LDS (C-layout write), read back as A-fragments
        bf16* pw = Ps[wave];
#pragma unroll
        for (int n = 0; n < 4; ++n)
#pragma unroll
            for (int j = 0; j < 4; ++j)
                pw[(grp * 4 + j) * LDK + n * 16 + row16] = (bf16)p[n][j];
        asm volatile("" ::: "memory");  // keep ds_writes before ds_reads

        const bf16x8 pa0 = ld8(&pw[row16 * LDK + grp * 8]);
        const bf16x8 pa1 = ld8(&pw[row16 * LDK + 32 + grp * 8]);
#pragma unroll
        for (int n = 0; n < 4; ++n) {
            o[n] = mfma16(pa0, ld8(&VTs[(n * 16 + row16) * LDK + grp * 8]), o[n]);
            o[n] = mfma16(pa1, ld8(&VTs[(n * 16 + row16) * LDK + 32 + grp * 8]), o[n]);
        }
    }

    // epilogue: O[token][h*64 + d] bf16
    bf16* orow = O + (size_t)(b * SEQ + q0 + wave * 16 + grp * 4) * DM + hoff + row16;
#pragma unroll
    for (int j = 0; j < 4; ++j) {
        const float inv = 1.0f / lrow[j];
#pragma unroll
        for (int n = 0; n < 4; ++n)
            orow[(size_t)j * DM + n * 16] = (bf16)(o[n][j] * inv);
    }
}

// ---------------- launch ----------------
extern "C" void kernel_launch(void* const* d_in, const int* in_sizes, int n_in,
                              void* d_out, int out_size, void* d_ws, size_t ws_size,
                              hipStream_t stream) {
    const float* x  = (const float*)d_in[0];
    const float* Wq = (const float*)d_in[1];
    const float* bq = (const float*)d_in[2];
    const float* Wk = (const float*)d_in[3];
    const float* bk = (const float*)d_in[4];
    const float* Wv = (const float*)d_in[5];
    const float* bv = (const float*)d_in[6];
    const float* Wo = (const float*)d_in[7];
    const float* bo = (const float*)d_in[8];
    float* out = (float*)d_out;

    // workspace layout (bytes), total 48 MB
    char* ws = (char*)d_ws;
    bf16* xb  = (bf16*)(ws + 0);           // 8 MB  x as bf16
    bf16* wqb = (bf16*)(ws + 8388608);     // 2 MB
    bf16* wkb = (bf16*)(ws + 10485760);    // 2 MB
    bf16* wvb = (bf16*)(ws + 12582912);    // 2 MB
    bf16* wob = (bf16*)(ws + 14680064);    // 2 MB
    bf16* qb  = (bf16*)(ws + 16777216);    // 8 MB
    bf16* kb  = (bf16*)(ws + 25165824);    // 8 MB
    bf16* vb  = (bf16*)(ws + 33554432);    // 8 MB
    bf16* ab  = (bf16*)(ws + 41943040);    // 8 MB  attention output (token-major)

    // casts
    cvt4<<<4096, 256, 0, stream>>>((const float4*)x,  (ushort4*)xb,  1048576);
    cvt4<<<1024, 256, 0, stream>>>((const float4*)Wq, (ushort4*)wqb, 262144);
    cvt4<<<1024, 256, 0, stream>>>((const float4*)Wk, (ushort4*)wkb, 262144);
    cvt4<<<1024, 256, 0, stream>>>((const float4*)Wv, (ushort4*)wvb, 262144);
    cvt4<<<1024, 256, 0, stream>>>((const float4*)Wo, (ushort4*)wob, 262144);

    // fused QKV projection: grid.y selects {Wq,Wk,Wv} x 8 N-tiles
    gemm_qkv<<<dim3(32, 24), 256, 0, stream>>>(xb, wqb, wkb, wvb, bq, bk, bv, qb, kb, vb);

    // flash attention
    attn<<<dim3(32, 16, 2), 256, 0, stream>>>(qb, kb, vb, ab);

    // output projection (fp32 out)
    gemm_out<<<dim3(32, 8), 256, 0, stream>>>(ab, wob, bo, out);
}

// Round 2
// 173.948 us; speedup vs baseline: 1.4542x; 1.4542x over previous
//
#include <hip/hip_runtime.h>
#include <hip/hip_bf16.h>
#include <cstdint>

typedef __bf16 bf16;
typedef __bf16 bf16x8 __attribute__((ext_vector_type(8)));
typedef float f32x4 __attribute__((ext_vector_type(4)));

#define DM   1024
#define SEQ  2048
#define NH   16
#define DKH  64

__device__ __forceinline__ bf16x8 ld8(const bf16* p) {
    return *reinterpret_cast<const bf16x8*>(p);
}

// async global->LDS, 16B per lane (wave-uniform LDS base + lane*16 layout)
__device__ __forceinline__ void gld16(const void* g, void* lds) {
    __builtin_amdgcn_global_load_lds(
        (__attribute__((address_space(1))) void*)(uintptr_t)g,
        (__attribute__((address_space(3))) void*)(uint32_t)(uintptr_t)lds,
        16, 0, 0);
}

__device__ __forceinline__ f32x4 mfma16(bf16x8 a, bf16x8 b, f32x4 c) {
    return __builtin_amdgcn_mfma_f32_16x16x32_bf16(a, b, c, 0, 0, 0);
}

// ---------------- fp32 -> bf16 cast (vectorized) ----------------
__global__ __launch_bounds__(256) void cvt4(const float4* __restrict__ src,
                                            ushort4* __restrict__ dst, int n4) {
    int i = blockIdx.x * 256 + threadIdx.x;
    if (i >= n4) return;
    float4 f = src[i];
    ushort4 u;
    u.x = __builtin_bit_cast(unsigned short, (bf16)f.x);
    u.y = __builtin_bit_cast(unsigned short, (bf16)f.y);
    u.z = __builtin_bit_cast(unsigned short, (bf16)f.z);
    u.w = __builtin_bit_cast(unsigned short, (bf16)f.w);
    dst[i] = u;
}

// ---------------- GEMM: y = A @ W^T + bias (128x128 tile, BK=64) -------------
template <bool OUT_F32>
__device__ __forceinline__ void gemm_body(const bf16* __restrict__ A,
                                          const bf16* __restrict__ W,
                                          const float* __restrict__ bias,
                                          void* __restrict__ outp,
                                          int m0, int n0) {
    constexpr int K = DM, BK = 64;
    __shared__ __attribute__((aligned(16))) bf16 As[128 * BK];
    __shared__ __attribute__((aligned(16))) bf16 Bs[128 * BK];

    const int t     = threadIdx.x;
    const int lane  = t & 63;
    const int row16 = lane & 15, grp = lane >> 4;
    const int wave  = t >> 6;
    const int wr    = (wave >> 1) * 64;
    const int wc    = (wave & 1) * 64;

    f32x4 acc[4][4] = {};

    const int sc = (t & 7) * 8;
    const bf16* Ag = A + (size_t)(m0 + (t >> 3)) * K + sc;
    const bf16* Wg = W + (size_t)(n0 + (t >> 3)) * K + sc;
    bf16* Asw = &As[t * 8];
    bf16* Bsw = &Bs[t * 8];

    for (int kt = 0; kt < K; kt += BK) {
        __syncthreads();
#pragma unroll
        for (int i = 0; i < 4; ++i) {
            gld16(Ag + (size_t)i * 32 * K + kt, Asw + i * 2048);
            gld16(Wg + (size_t)i * 32 * K + kt, Bsw + i * 2048);
        }
        __syncthreads();
#pragma unroll
        for (int kk = 0; kk < BK; kk += 32) {
            bf16x8 af[4], bfr[4];
#pragma unroll
            for (int m = 0; m < 4; ++m)
                af[m] = ld8(&As[(wr + m * 16 + row16) * BK + kk + grp * 8]);
#pragma unroll
            for (int n = 0; n < 4; ++n)
                bfr[n] = ld8(&Bs[(wc + n * 16 + row16) * BK + kk + grp * 8]);
#pragma unroll
            for (int m = 0; m < 4; ++m)
#pragma unroll
                for (int n = 0; n < 4; ++n)
                    acc[m][n] = mfma16(af[m], bfr[n], acc[m][n]);
        }
    }

#pragma unroll
    for (int n = 0; n < 4; ++n) {
        const int col = n0 + wc + n * 16 + row16;
        const float bv = bias[col];
#pragma unroll
        for (int m = 0; m < 4; ++m) {
            const int row = m0 + wr + m * 16 + grp * 4;
#pragma unroll
            for (int j = 0; j < 4; ++j) {
                float v = acc[m][n][j] + bv;
                if constexpr (OUT_F32)
                    ((float*)outp)[(size_t)(row + j) * DM + col] = v;
                else
                    ((bf16*)outp)[(size_t)(row + j) * DM + col] = (bf16)v;
            }
        }
    }
}

__global__ __launch_bounds__(256) void gemm_qkv(
    const bf16* __restrict__ xb,
    const bf16* __restrict__ wqb, const bf16* __restrict__ wkb, const bf16* __restrict__ wvb,
    const float* __restrict__ bq, const float* __restrict__ bk, const float* __restrict__ bv,
    bf16* __restrict__ q, bf16* __restrict__ k, bf16* __restrict__ v) {
    const int sel = blockIdx.y >> 3;
    const bf16* W    = sel == 0 ? wqb : (sel == 1 ? wkb : wvb);
    const float* bia = sel == 0 ? bq  : (sel == 1 ? bk  : bv);
    bf16* out        = sel == 0 ? q   : (sel == 1 ? k   : v);
    gemm_body<false>(xb, W, bia, out, blockIdx.x * 128, (blockIdx.y & 7) * 128);
}

__global__ __launch_bounds__(256) void gemm_out(
    const bf16* __restrict__ ab, const bf16* __restrict__ wob,
    const float* __restrict__ bo, float* __restrict__ out) {
    gemm_body<true>(ab, wob, bo, out, blockIdx.x * 128, blockIdx.y * 128);
}

// ---------------- V transpose: v[tok][h*64+d] -> vt[(b*16+h)*64+d][tok] -------
__global__ __launch_bounds__(256) void transpV(const bf16* __restrict__ v,
                                               bf16* __restrict__ vt) {
    __shared__ __attribute__((aligned(16))) bf16 T[64 * 64];
    const int t = threadIdx.x;
    const int s0 = blockIdx.x * 64, h = blockIdx.y, b = blockIdx.z;
    const int r = t >> 3, c = t & 7;
#pragma unroll
    for (int i = 0; i < 2; ++i) {
        const int row = i * 32 + r;  // token within tile
        bf16x8 val = ld8(v + (size_t)(b * SEQ + s0 + row) * DM + h * DKH + c * 8);
        const int slot = c ^ ((row ^ (row >> 3)) & 7);
        *reinterpret_cast<bf16x8*>(&T[row * 64 + slot * 8]) = val;
    }
    __syncthreads();
#pragma unroll
    for (int i = 0; i < 2; ++i) {
        const int d = i * 32 + r;
        bf16 tmp[8];
#pragma unroll
        for (int j = 0; j < 8; ++j) {
            const int tok = c * 8 + j;
            tmp[j] = T[tok * 64 + (d ^ (((tok ^ (tok >> 3)) & 7) << 3))];
        }
        *reinterpret_cast<bf16x8*>(vt + (size_t)((b * NH + h) * DKH + d) * SEQ + s0 + c * 8) =
            *reinterpret_cast<bf16x8*>(tmp);
    }
}

// ---------------- flash attention v2 ----------------
// 1-D grid 512 blocks (XCD-swizzled), 4 waves x 32 q-rows = 128 q/block.
// K and pre-transposed V^T staged via global_load_lds with pre-swizzled source
// (slot ^= row&7 within 128-B rows); double-buffered, 1 barrier/tile.
// Softmax in exp2 domain with defer-max (T13).
__global__ __launch_bounds__(256) void attn(const bf16* __restrict__ Q,
                                            const bf16* __restrict__ K,
                                            const bf16* __restrict__ VT,
                                            bf16* __restrict__ O) {
    constexpr float C1 = 0.18033688f;   // (1/8) * log2(e)
    constexpr float THR2 = 10.0f;       // defer-max threshold (log2 units)
    __shared__ __attribute__((aligned(16))) bf16 Ks[2][64 * 64];
    __shared__ __attribute__((aligned(16))) bf16 Vs[2][64 * 64];
    __shared__ __attribute__((aligned(16))) bf16 Ps[4][16 * 64];

    const int t = threadIdx.x, lane = t & 63, wave = t >> 6;
    const int r16 = lane & 15, g = lane >> 4;

    // XCD swizzle: contiguous 64-block chunk (= 4 whole heads) per XCD
    int id = blockIdx.x;
    id = (id & 7) * 64 + (id >> 3);
    const int qt = id & 15, h = (id >> 4) & 15, b = id >> 8;

    const bf16* Qb = Q + ((size_t)b * SEQ + qt * 128) * DM + h * DKH;
    const bf16* Kb = K + (size_t)b * SEQ * DM + h * DKH;
    const bf16* Vb = VT + (size_t)((b * NH + h) * DKH) * SEQ;  // [64 d][2048 kv]

    // Q A-fragments: 2 q-subs x 2 k-chunks
    bf16x8 qf[2][2];
#pragma unroll
    for (int u = 0; u < 2; ++u)
#pragma unroll
        for (int p = 0; p < 2; ++p)
            qf[u][p] = ld8(Qb + (size_t)(wave * 32 + u * 16 + r16) * DM + p * 32 + g * 8);

    f32x4 o[2][4] = {};
    float M[2][4], L[2][4];
#pragma unroll
    for (int u = 0; u < 2; ++u)
#pragma unroll
        for (int j = 0; j < 4; ++j) { M[u][j] = -1e30f; L[u][j] = 0.f; }

    const int sr = t >> 3, scs = t & 7;

    auto STAGE = [&](int bsel, int kt) {
#pragma unroll
        for (int i = 0; i < 2; ++i) {
            const int r = i * 32 + sr;
            const int cs = (scs ^ (r & 7)) * 8;  // pre-swizzled source slot
            gld16(Kb + (size_t)(kt + r) * DM + cs, &Ks[bsel][i * 2048 + t * 8]);
            gld16(Vb + (size_t)r * SEQ + kt + cs, &Vs[bsel][i * 2048 + t * 8]);
        }
    };

    STAGE(0, 0);
    __syncthreads();

    int cur = 0;
    for (int kt = 0; kt < SEQ; kt += 64) {
        if (kt + 64 < SEQ) STAGE(cur ^ 1, kt + 64);
        const bf16* KsB = Ks[cur];
        const bf16* VsB = Vs[cur];

        // ---- QK^T ----
        f32x4 s[2][4];
#pragma unroll
        for (int n = 0; n < 4; ++n) {
            const int row = n * 16 + r16;
            const bf16x8 kf0 = ld8(&KsB[row * 64 + ((g) ^ (row & 7)) * 8]);
            const bf16x8 kf1 = ld8(&KsB[row * 64 + ((4 + g) ^ (row & 7)) * 8]);
#pragma unroll
            for (int u = 0; u < 2; ++u) {
                f32x4 a = {};
                a = mfma16(qf[u][0], kf0, a);
                a = mfma16(qf[u][1], kf1, a);
                s[u][n] = a;
            }
        }

        // ---- V^T B-fragments (shared across q-subs) ----
        bf16x8 vtf[4][2];
#pragma unroll
        for (int n = 0; n < 4; ++n) {
            const int row = n * 16 + r16;
#pragma unroll
            for (int p = 0; p < 2; ++p)
                vtf[n][p] = ld8(&VsB[row * 64 + ((p * 4 + g) ^ (row & 7)) * 8]);
        }

        // ---- defer-max check ----
        float tl[2][4];
        bool okb = true;
#pragma unroll
        for (int u = 0; u < 2; ++u)
#pragma unroll
            for (int j = 0; j < 4; ++j) {
                tl[u][j] = fmaxf(fmaxf(s[u][0][j], s[u][1][j]),
                                 fmaxf(s[u][2][j], s[u][3][j])) * C1;
                okb = okb && (tl[u][j] <= M[u][j] + THR2);
            }
        if (!__all(okb)) {   // rare: full max-reduce + rescale
#pragma unroll
            for (int u = 0; u < 2; ++u)
#pragma unroll
                for (int j = 0; j < 4; ++j) {
                    float tm = tl[u][j];
#pragma unroll
                    for (int msk = 1; msk < 16; msk <<= 1)
                        tm = fmaxf(tm, __shfl_xor(tm, msk));
                    const float Mn = fmaxf(M[u][j], tm);
                    const float al = __builtin_amdgcn_exp2f(M[u][j] - Mn);
                    M[u][j] = Mn;
                    L[u][j] *= al;
#pragma unroll
                    for (int n = 0; n < 4; ++n) o[u][n][j] *= al;
                }
        }

        // ---- per-sub: exp, P->LDS, row-sum, PV ----
        bf16* Pw = Ps[wave];
#pragma unroll
        for (int u = 0; u < 2; ++u) {
            float rs[4] = {};
#pragma unroll
            for (int n = 0; n < 4; ++n) {
                const int kv = n * 16 + r16;
#pragma unroll
                for (int j = 0; j < 4; ++j) {
                    const float v = __builtin_amdgcn_exp2f(fmaf(s[u][n][j], C1, -M[u][j]));
                    rs[j] += v;
                    const int q = 4 * g + j;
                    Pw[q * 64 + (kv ^ ((q & 7) << 3))] = (bf16)v;
                }
            }
#pragma unroll
            for (int msk = 1; msk < 16; msk <<= 1)
#pragma unroll
                for (int j = 0; j < 4; ++j) rs[j] += __shfl_xor(rs[j], msk);
#pragma unroll
            for (int j = 0; j < 4; ++j) L[u][j] += rs[j];

            asm volatile("" ::: "memory");
            const int sw = (r16 & 7) << 3;
            const bf16x8 pa0 = ld8(&Pw[r16 * 64 + ((g * 8) ^ sw)]);
            const bf16x8 pa1 = ld8(&Pw[r16 * 64 + ((32 + g * 8) ^ sw)]);
#pragma unroll
            for (int n = 0; n < 4; ++n) {
                o[u][n] = mfma16(pa0, vtf[n][0], o[u][n]);
                o[u][n] = mfma16(pa1, vtf[n][1], o[u][n]);
            }
            asm volatile("" ::: "memory");  // order sub1 P-writes after sub0 reads
        }

        __syncthreads();
        cur ^= 1;
    }

    // ---- epilogue ----
#pragma unroll
    for (int u = 0; u < 2; ++u)
#pragma unroll
        for (int j = 0; j < 4; ++j) {
            const float inv = 1.0f / L[u][j];
            bf16* orow = O + ((size_t)b * SEQ + qt * 128 + wave * 32 + u * 16 + g * 4 + j) * DM
                         + h * DKH + r16;
#pragma unroll
            for (int n = 0; n < 4; ++n)
                orow[n * 16] = (bf16)(o[u][n][j] * inv);
        }
}

// ---------------- launch ----------------
extern "C" void kernel_launch(void* const* d_in, const int* in_sizes, int n_in,
                              void* d_out, int out_size, void* d_ws, size_t ws_size,
                              hipStream_t stream) {
    const float* x  = (const float*)d_in[0];
    const float* Wq = (const float*)d_in[1];
    const float* bq = (const float*)d_in[2];
    const float* Wk = (const float*)d_in[3];
    const float* bk = (const float*)d_in[4];
    const float* Wv = (const float*)d_in[5];
    const float* bv = (const float*)d_in[6];
    const float* Wo = (const float*)d_in[7];
    const float* bo = (const float*)d_in[8];
    float* out = (float*)d_out;

    // workspace layout (bytes), total 48 MB; ab overlays vb (dead after transpV)
    char* ws = (char*)d_ws;
    bf16* xb  = (bf16*)(ws + 0);           // 8 MB
    bf16* wqb = (bf16*)(ws + 8388608);     // 2 MB
    bf16* wkb = (bf16*)(ws + 10485760);    // 2 MB
    bf16* wvb = (bf16*)(ws + 12582912);    // 2 MB
    bf16* wob = (bf16*)(ws + 14680064);    // 2 MB
    bf16* qb  = (bf16*)(ws + 16777216);    // 8 MB
    bf16* kb  = (bf16*)(ws + 25165824);    // 8 MB
    bf16* vb  = (bf16*)(ws + 33554432);    // 8 MB (row-major V, then reused as ab)
    bf16* vtb = (bf16*)(ws + 41943040);    // 8 MB (V^T)
    bf16* ab  = vb;                        // attention output overlays vb

    cvt4<<<4096, 256, 0, stream>>>((const float4*)x,  (ushort4*)xb,  1048576);
    cvt4<<<1024, 256, 0, stream>>>((const float4*)Wq, (ushort4*)wqb, 262144);
    cvt4<<<1024, 256, 0, stream>>>((const float4*)Wk, (ushort4*)wkb, 262144);
    cvt4<<<1024, 256, 0, stream>>>((const float4*)Wv, (ushort4*)wvb, 262144);
    cvt4<<<1024, 256, 0, stream>>>((const float4*)Wo, (ushort4*)wob, 262144);

    gemm_qkv<<<dim3(32, 24), 256, 0, stream>>>(xb, wqb, wkb, wvb, bq, bk, bv, qb, kb, vb);

    transpV<<<dim3(32, 16, 2), 256, 0, stream>>>(vb, vtb);

    attn<<<dim3(512), 256, 0, stream>>>(qb, kb, vtb, ab);

    gemm_out<<<dim3(32, 8), 256, 0, stream>>>(ab, wob, bo, out);
}

// Round 3
// 142.354 us; speedup vs baseline: 1.7770x; 1.2219x over previous
//
#include <hip/hip_runtime.h>
#include <hip/hip_bf16.h>
#include <cstdint>

typedef __bf16 bf16;
typedef __bf16 bf16x4 __attribute__((ext_vector_type(4)));
typedef __bf16 bf16x8 __attribute__((ext_vector_type(8)));
typedef float f32x4 __attribute__((ext_vector_type(4)));

#define DM   1024
#define SEQ  2048
#define NH   16
#define DKH  64

__device__ __forceinline__ bf16x8 ld8(const bf16* p) {
    return *reinterpret_cast<const bf16x8*>(p);
}

// async global->LDS, 16B per lane (wave-uniform LDS base + lane*16 layout)
__device__ __forceinline__ void gld16(const void* g, void* lds) {
    __builtin_amdgcn_global_load_lds(
        (__attribute__((address_space(1))) void*)(uintptr_t)g,
        (__attribute__((address_space(3))) void*)(uint32_t)(uintptr_t)lds,
        16, 0, 0);
}

__device__ __forceinline__ f32x4 mfma16(bf16x8 a, bf16x8 b, f32x4 c) {
    return __builtin_amdgcn_mfma_f32_16x16x32_bf16(a, b, c, 0, 0, 0);
}

// ---------------- fused fp32 -> bf16 casts (x + 4 weights, one launch) -------
__global__ __launch_bounds__(256) void cvt_all(
    const float4* __restrict__ x,  const float4* __restrict__ wq,
    const float4* __restrict__ wk, const float4* __restrict__ wv,
    const float4* __restrict__ wo,
    ushort4* __restrict__ xb,  ushort4* __restrict__ wqb,
    ushort4* __restrict__ wkb, ushort4* __restrict__ wvb,
    ushort4* __restrict__ wob) {
    int i = blockIdx.x * 256 + threadIdx.x;   // 2M float4 total
    const float4* src;
    ushort4* dst;
    int off;
    if (i < 1048576) {
        src = x; dst = xb; off = i;
    } else {
        int r = i - 1048576;
        int sel = r >> 18;          // 4 weight regions of 256K float4
        off = r & 262143;
        src = sel == 0 ? wq : sel == 1 ? wk : sel == 2 ? wv : wo;
        dst = sel == 0 ? wqb : sel == 1 ? wkb : sel == 2 ? wvb : wob;
    }
    float4 f = src[off];
    ushort4 u;
    u.x = __builtin_bit_cast(unsigned short, (bf16)f.x);
    u.y = __builtin_bit_cast(unsigned short, (bf16)f.y);
    u.z = __builtin_bit_cast(unsigned short, (bf16)f.z);
    u.w = __builtin_bit_cast(unsigned short, (bf16)f.w);
    dst[off] = u;
}

// ---------------- GEMM: y = A @ W^T + bias (128x128 tile, BK=64) -------------
template <bool OUT_F32>
__device__ __forceinline__ void gemm_body(const bf16* __restrict__ A,
                                          const bf16* __restrict__ W,
                                          const float* __restrict__ bias,
                                          void* __restrict__ outp,
                                          int m0, int n0) {
    constexpr int K = DM, BK = 64;
    __shared__ __attribute__((aligned(16))) bf16 As[128 * BK];
    __shared__ __attribute__((aligned(16))) bf16 Bs[128 * BK];

    const int t     = threadIdx.x;
    const int lane  = t & 63;
    const int row16 = lane & 15, grp = lane >> 4;
    const int wave  = t >> 6;
    const int wr    = (wave >> 1) * 64;
    const int wc    = (wave & 1) * 64;

    f32x4 acc[4][4] = {};

    const int sc = (t & 7) * 8;
    const bf16* Ag = A + (size_t)(m0 + (t >> 3)) * K + sc;
    const bf16* Wg = W + (size_t)(n0 + (t >> 3)) * K + sc;
    bf16* Asw = &As[t * 8];
    bf16* Bsw = &Bs[t * 8];

    for (int kt = 0; kt < K; kt += BK) {
        __syncthreads();
#pragma unroll
        for (int i = 0; i < 4; ++i) {
            gld16(Ag + (size_t)i * 32 * K + kt, Asw + i * 2048);
            gld16(Wg + (size_t)i * 32 * K + kt, Bsw + i * 2048);
        }
        __syncthreads();
#pragma unroll
        for (int kk = 0; kk < BK; kk += 32) {
            bf16x8 af[4], bfr[4];
#pragma unroll
            for (int m = 0; m < 4; ++m)
                af[m] = ld8(&As[(wr + m * 16 + row16) * BK + kk + grp * 8]);
#pragma unroll
            for (int n = 0; n < 4; ++n)
                bfr[n] = ld8(&Bs[(wc + n * 16 + row16) * BK + kk + grp * 8]);
#pragma unroll
            for (int m = 0; m < 4; ++m)
#pragma unroll
                for (int n = 0; n < 4; ++n)
                    acc[m][n] = mfma16(af[m], bfr[n], acc[m][n]);
        }
    }

#pragma unroll
    for (int n = 0; n < 4; ++n) {
        const int col = n0 + wc + n * 16 + row16;
        const float bv = bias[col];
#pragma unroll
        for (int m = 0; m < 4; ++m) {
            const int row = m0 + wr + m * 16 + grp * 4;
#pragma unroll
            for (int j = 0; j < 4; ++j) {
                float v = acc[m][n][j] + bv;
                if constexpr (OUT_F32)
                    ((float*)outp)[(size_t)(row + j) * DM + col] = v;
                else
                    ((bf16*)outp)[(size_t)(row + j) * DM + col] = (bf16)v;
            }
        }
    }
}

__global__ __launch_bounds__(256) void gemm_qkv(
    const bf16* __restrict__ xb,
    const bf16* __restrict__ wqb, const bf16* __restrict__ wkb, const bf16* __restrict__ wvb,
    const float* __restrict__ bq, const float* __restrict__ bk, const float* __restrict__ bv,
    bf16* __restrict__ q, bf16* __restrict__ k, bf16* __restrict__ v) {
    const int sel = blockIdx.y >> 3;
    const bf16* W    = sel == 0 ? wqb : (sel == 1 ? wkb : wvb);
    const float* bia = sel == 0 ? bq  : (sel == 1 ? bk  : bv);
    bf16* out        = sel == 0 ? q   : (sel == 1 ? k   : v);
    gemm_body<false>(xb, W, bia, out, blockIdx.x * 128, (blockIdx.y & 7) * 128);
}

__global__ __launch_bounds__(256) void gemm_out(
    const bf16* __restrict__ ab, const bf16* __restrict__ wob,
    const float* __restrict__ bo, float* __restrict__ out) {
    gemm_body<true>(ab, wob, bo, out, blockIdx.x * 128, blockIdx.y * 128);
}

// ---------------- V transpose: v[tok][h*64+d] -> vt[(b*16+h)*64+d][tok] -------
__global__ __launch_bounds__(256) void transpV(const bf16* __restrict__ v,
                                               bf16* __restrict__ vt) {
    __shared__ __attribute__((aligned(16))) bf16 T[64 * 64];
    const int t = threadIdx.x;
    const int s0 = blockIdx.x * 64, h = blockIdx.y, b = blockIdx.z;
    const int r = t >> 3, c = t & 7;
#pragma unroll
    for (int i = 0; i < 2; ++i) {
        const int row = i * 32 + r;  // token within tile
        bf16x8 val = ld8(v + (size_t)(b * SEQ + s0 + row) * DM + h * DKH + c * 8);
        const int slot = c ^ ((row ^ (row >> 3)) & 7);
        *reinterpret_cast<bf16x8*>(&T[row * 64 + slot * 8]) = val;
    }
    __syncthreads();
#pragma unroll
    for (int i = 0; i < 2; ++i) {
        const int d = i * 32 + r;
        bf16 tmp[8];
#pragma unroll
        for (int j = 0; j < 8; ++j) {
            const int tok = c * 8 + j;
            tmp[j] = T[tok * 64 + (d ^ (((tok ^ (tok >> 3)) & 7) << 3))];
        }
        *reinterpret_cast<bf16x8*>(vt + (size_t)((b * NH + h) * DKH + d) * SEQ + s0 + c * 8) =
            *reinterpret_cast<bf16x8*>(tmp);
    }
}

// ---------------- flash attention v3: swapped QK^T, lane-local softmax -------
// grid 512 (XCD-swizzled), 4 waves x 32 q-rows. S^T = mfma(Kf, Qf) puts each
// lane's 16 P values on ONE q-row (r16): per-lane partial L (epilogue reduce),
// defer-max with lane-local check, vectorized b64 P round-trip.
__global__ __launch_bounds__(256) void attn(const bf16* __restrict__ Q,
                                            const bf16* __restrict__ K,
                                            const bf16* __restrict__ VT,
                                            bf16* __restrict__ O) {
    constexpr float C1 = 0.18033688f;   // (1/8) * log2(e)
    constexpr float THR2 = 10.0f;       // defer-max threshold (log2 units)
    __shared__ __attribute__((aligned(16))) bf16 Ks[2][64 * 64];
    __shared__ __attribute__((aligned(16))) bf16 Vs[2][64 * 64];
    __shared__ __attribute__((aligned(16))) bf16 Ps[4][16 * 64];

    const int t = threadIdx.x, lane = t & 63, wave = t >> 6;
    const int r16 = lane & 15, g = lane >> 4;

    int id = blockIdx.x;
    id = (id & 7) * 64 + (id >> 3);
    const int qt = id & 15, h = (id >> 4) & 15, b = id >> 8;

    const bf16* Qb = Q + ((size_t)b * SEQ + qt * 128) * DM + h * DKH;
    const bf16* Kb = K + (size_t)b * SEQ * DM + h * DKH;
    const bf16* Vb = VT + (size_t)((b * NH + h) * DKH) * SEQ;  // [64 d][2048 kv]

    bf16x8 qf[2][2];
#pragma unroll
    for (int u = 0; u < 2; ++u)
#pragma unroll
        for (int p = 0; p < 2; ++p)
            qf[u][p] = ld8(Qb + (size_t)(wave * 32 + u * 16 + r16) * DM + p * 32 + g * 8);

    f32x4 o[2][4] = {};
    float M[2] = {-1e30f, -1e30f};
    float Lp[2] = {0.f, 0.f};   // per-lane partial row-sum (q-row r16 domain)

    const int sr = t >> 3, scs = t & 7;

    auto STAGE = [&](int bsel, int kt) {
#pragma unroll
        for (int i = 0; i < 2; ++i) {
            const int r = i * 32 + sr;
            const int cs = (scs ^ (r & 7)) * 8;  // pre-swizzled source slot
            gld16(Kb + (size_t)(kt + r) * DM + cs, &Ks[bsel][i * 2048 + t * 8]);
            gld16(Vb + (size_t)r * SEQ + kt + cs, &Vs[bsel][i * 2048 + t * 8]);
        }
    };

    STAGE(0, 0);
    __syncthreads();

    int cur = 0;
    for (int kt = 0; kt < SEQ; kt += 64) {
        if (kt + 64 < SEQ) STAGE(cur ^ 1, kt + 64);
        const bf16* KsB = Ks[cur];
        const bf16* VsB = Vs[cur];

        // ---- swapped QK^T: S^T[kv][q], lane(r16,g): q=r16, kv=n*16+g*4+j ----
        f32x4 s[2][4];
#pragma unroll
        for (int n = 0; n < 4; ++n) {
            const int row = n * 16 + r16;
            const bf16x8 kf0 = ld8(&KsB[row * 64 + ((g) ^ (row & 7)) * 8]);
            const bf16x8 kf1 = ld8(&KsB[row * 64 + ((4 + g) ^ (row & 7)) * 8]);
#pragma unroll
            for (int u = 0; u < 2; ++u) {
                f32x4 a = {};
                a = mfma16(kf0, qf[u][0], a);
                a = mfma16(kf1, qf[u][1], a);
                s[u][n] = a;
            }
        }

        // ---- V^T B-fragments ----
        bf16x8 vtf[4][2];
#pragma unroll
        for (int n = 0; n < 4; ++n) {
            const int row = n * 16 + r16;
#pragma unroll
            for (int p = 0; p < 2; ++p)
                vtf[n][p] = ld8(&VsB[row * 64 + ((p * 4 + g) ^ (row & 7)) * 8]);
        }

        // ---- defer-max: lane-local max check ----
        float lm[2];
#pragma unroll
        for (int u = 0; u < 2; ++u) {
            float a0 = fmaxf(fmaxf(s[u][0][0], s[u][0][1]), fmaxf(s[u][0][2], s[u][0][3]));
            float a1 = fmaxf(fmaxf(s[u][1][0], s[u][1][1]), fmaxf(s[u][1][2], s[u][1][3]));
            float a2 = fmaxf(fmaxf(s[u][2][0], s[u][2][1]), fmaxf(s[u][2][2], s[u][2][3]));
            float a3 = fmaxf(fmaxf(s[u][3][0], s[u][3][1]), fmaxf(s[u][3][2], s[u][3][3]));
            lm[u] = fmaxf(fmaxf(a0, a1), fmaxf(a2, a3)) * C1;
        }
        bool ok = (lm[0] <= M[0] + THR2) && (lm[1] <= M[1] + THR2);
        if (!__all(ok)) {   // rare: full row-max across the 4 sharing lanes
#pragma unroll
            for (int u = 0; u < 2; ++u) {
                float tm = lm[u];
                tm = fmaxf(tm, __shfl_xor(tm, 16));
                tm = fmaxf(tm, __shfl_xor(tm, 32));
                const float Mn = fmaxf(M[u], tm);
                const float al = __builtin_amdgcn_exp2f(M[u] - Mn);
                M[u] = Mn;
                Lp[u] *= al;
                float alj[4];
#pragma unroll
                for (int j = 0; j < 4; ++j) alj[j] = __shfl(al, g * 4 + j);
#pragma unroll
                for (int n = 0; n < 4; ++n)
#pragma unroll
                    for (int j = 0; j < 4; ++j) o[u][n][j] *= alj[j];
            }
        }

        // ---- per-sub: exp (lane-local), pack, b64 write, read pa, PV ----
        bf16* Pw = Ps[wave];
        const int sw = r16 & 7;
#pragma unroll
        for (int u = 0; u < 2; ++u) {
#pragma unroll
            for (int n = 0; n < 4; ++n) {
                f32x4 pv;
#pragma unroll
                for (int j = 0; j < 4; ++j)
                    pv[j] = __builtin_amdgcn_exp2f(fmaf(s[u][n][j], C1, -M[u]));
                Lp[u] += (pv[0] + pv[1]) + (pv[2] + pv[3]);
                bf16x4 w4 = {(bf16)pv[0], (bf16)pv[1], (bf16)pv[2], (bf16)pv[3]};
                const int slot = (n * 2 + (g >> 1)) ^ sw;
                *reinterpret_cast<bf16x4*>(&Pw[r16 * 64 + slot * 8 + (g & 1) * 4]) = w4;
            }
            asm volatile("" ::: "memory");
            const bf16x8 pa0 = ld8(&Pw[r16 * 64 + ((g ^ sw) * 8)]);
            const bf16x8 pa1 = ld8(&Pw[r16 * 64 + (((4 + g) ^ sw) * 8)]);
#pragma unroll
            for (int n = 0; n < 4; ++n) {
                o[u][n] = mfma16(pa0, vtf[n][0], o[u][n]);
                o[u][n] = mfma16(pa1, vtf[n][1], o[u][n]);
            }
            asm volatile("" ::: "memory");  // order next-u writes after reads
        }

        __syncthreads();
        cur ^= 1;
    }

    // ---- epilogue: reduce per-lane L across the 4 sharing lanes, remap ----
#pragma unroll
    for (int u = 0; u < 2; ++u) {
        float Lt = Lp[u];
        Lt += __shfl_xor(Lt, 16);
        Lt += __shfl_xor(Lt, 32);   // Lt = full L for q-row r16
        float inv[4];
#pragma unroll
        for (int j = 0; j < 4; ++j)
            inv[j] = 1.0f / __shfl(Lt, g * 4 + j);   // L for this lane's o-rows
#pragma unroll
        for (int j = 0; j < 4; ++j) {
            bf16* orow = O + ((size_t)b * SEQ + qt * 128 + wave * 32 + u * 16 + g * 4 + j) * DM
                         + h * DKH + r16;
#pragma unroll
            for (int n = 0; n < 4; ++n)
                orow[n * 16] = (bf16)(o[u][n][j] * inv[j]);
        }
    }
}

// ---------------- launch ----------------
extern "C" void kernel_launch(void* const* d_in, const int* in_sizes, int n_in,
                              void* d_out, int out_size, void* d_ws, size_t ws_size,
                              hipStream_t stream) {
    const float* x  = (const float*)d_in[0];
    const float* Wq = (const float*)d_in[1];
    const float* bq = (const float*)d_in[2];
    const float* Wk = (const float*)d_in[3];
    const float* bk = (const float*)d_in[4];
    const float* Wv = (const float*)d_in[5];
    const float* bv = (const float*)d_in[6];
    const float* Wo = (const float*)d_in[7];
    const float* bo = (const float*)d_in[8];
    float* out = (float*)d_out;

    char* ws = (char*)d_ws;
    bf16* xb  = (bf16*)(ws + 0);           // 8 MB
    bf16* wqb = (bf16*)(ws + 8388608);     // 2 MB
    bf16* wkb = (bf16*)(ws + 10485760);    // 2 MB
    bf16* wvb = (bf16*)(ws + 12582912);    // 2 MB
    bf16* wob = (bf16*)(ws + 14680064);    // 2 MB
    bf16* qb  = (bf16*)(ws + 16777216);    // 8 MB
    bf16* kb  = (bf16*)(ws + 25165824);    // 8 MB
    bf16* vb  = (bf16*)(ws + 33554432);    // 8 MB (row-major V, then reused as ab)
    bf16* vtb = (bf16*)(ws + 41943040);    // 8 MB (V^T)
    bf16* ab  = vb;                        // attention output overlays vb

    cvt_all<<<8192, 256, 0, stream>>>(
        (const float4*)x, (const float4*)Wq, (const float4*)Wk,
        (const float4*)Wv, (const float4*)Wo,
        (ushort4*)xb, (ushort4*)wqb, (ushort4*)wkb, (ushort4*)wvb, (ushort4*)wob);

    gemm_qkv<<<dim3(32, 24), 256, 0, stream>>>(xb, wqb, wkb, wvb, bq, bk, bv, qb, kb, vb);

    transpV<<<dim3(32, 16, 2), 256, 0, stream>>>(vb, vtb);

    attn<<<dim3(512), 256, 0, stream>>>(qb, kb, vtb, ab);

    gemm_out<<<dim3(32, 8), 256, 0, stream>>>(ab, wob, bo, out);
}